// Round 16
// baseline (152.960 us; speedup 1.0000x reference)
//
#include <hip/hip_runtime.h>
#include <hip/hip_bf16.h>
#include <cstdint>

#define HH 4
#define CC 64
#define KDIM 256   // IN_CH
#define NOUT 256   // H*C
#define BM 64
#define BK 64
#define CAP 64     // max degree capacity (Poisson(16): P(deg>=64) ~ 2e-18)

typedef __attribute__((ext_vector_type(8))) short bf16x8;
typedef __attribute__((ext_vector_type(4))) float f32x4;
typedef unsigned short ushort_t;

__device__ __forceinline__ unsigned short f2bf(float f) {
  unsigned u = __float_as_uint(f);
  unsigned r = (u + 0x7fff + ((u >> 16) & 1)) >> 16;  // RNE
  return (unsigned short)r;
}
__device__ __forceinline__ unsigned pk2bf(float lo, float hi) {
  return (unsigned)f2bf(lo) | ((unsigned)f2bf(hi) << 16);
}

// ---------------- pure bucket-CSR scatter ----------------
__global__ __launch_bounds__(256)
void scatter_k(const int* __restrict__ ei, int* __restrict__ cnt,
               int* __restrict__ bucket, int E) {
  int t = (int)blockIdx.x * 256 + threadIdx.x;
  if (t < E) {
    int s = ei[t];
    int d = ei[E + t];
    int pos = atomicAdd(&cnt[d], 1);
    if (pos < CAP) bucket[(size_t)d * CAP + pos] = s;
  }
}

// ---------------- MFMA GEMM 64x256: Wh(bf16) = x(fp32) @ W(fp32)^T + fused scores ----------------
// One block = 64 rows x all 256 cols; wave w owns head w. x read exactly once.
// x tile register-double-buffered: f_next issued before the barrier, consumed next iter
// (source-level only; no asm/sched directives — compiler schedules the waitcnts).
__global__ __launch_bounds__(256)
void gemm_direct(const float* __restrict__ X, const float* __restrict__ W,
                 ushort_t* __restrict__ Wh, float* __restrict__ s_src,
                 float* __restrict__ s_dst, const float* __restrict__ att,
                 int M, int* __restrict__ cnt, int N) {
  __shared__ char As[BM * BK * 2];       // 8 KB
  __shared__ char Bs[NOUT * BK * 2];     // 32 KB
  const int tid = threadIdx.x;
  const int lane = tid & 63;
  const int w = tid >> 6;
  const int row0 = blockIdx.x * BM;

  // zero cnt slice (next dispatch depends on it)
  if (tid < 64) {
    int i = (int)blockIdx.x * 64 + tid;
    if (i < N) cnt[i] = 0;
  }

  const int arow = tid >> 2;             // 0..63
  const int akoff = (tid & 3) * 16;
  const bool aval = (row0 + arow) < M;
  const float* gx = X + (size_t)(row0 + arow) * KDIM + akoff;

  f32x4 acc[4][4] = {};

  float4 f0, f1, f2, f3;                 // current x quad-row slice
  float4 n0, n1, n2, n3;                 // prefetched next
  {
    const float4 z = make_float4(0.f, 0.f, 0.f, 0.f);
    f0 = aval ? *(const float4*)(gx + 0)  : z;
    f1 = aval ? *(const float4*)(gx + 4)  : z;
    f2 = aval ? *(const float4*)(gx + 8)  : z;
    f3 = aval ? *(const float4*)(gx + 12) : z;
  }

#pragma unroll
  for (int k = 0; k < 4; ++k) {
    const int k0 = k * BK;
    // ---- stage A(k): regs -> bf16 -> swizzled LDS ----
    {
      uint4 o0, o1;
      o0.x = pk2bf(f0.x, f0.y); o0.y = pk2bf(f0.z, f0.w);
      o0.z = pk2bf(f1.x, f1.y); o0.w = pk2bf(f1.z, f1.w);
      o1.x = pk2bf(f2.x, f2.y); o1.y = pk2bf(f2.z, f2.w);
      o1.z = pk2bf(f3.x, f3.y); o1.w = pk2bf(f3.z, f3.w);
      int q0 = (tid & 3) * 2;
      *(uint4*)(As + (arow * 8 + (q0 ^ (arow & 7))) * 16) = o0;
      *(uint4*)(As + (arow * 8 + ((q0 + 1) ^ (arow & 7))) * 16) = o1;
    }
    // ---- stage B(k): 256x64 fp32 W -> bf16 LDS (L2-resident source) ----
#pragma unroll
    for (int i = 0; i < 8; ++i) {
      int c = i * 256 + tid;
      int row = c >> 3, q = c & 7;
      const float* gw = W + (size_t)row * KDIM + k0 + q * 8;
      float4 g0 = *(const float4*)gw;
      float4 g1 = *(const float4*)(gw + 4);
      uint4 o;
      o.x = pk2bf(g0.x, g0.y); o.y = pk2bf(g0.z, g0.w);
      o.z = pk2bf(g1.x, g1.y); o.w = pk2bf(g1.z, g1.w);
      int phys = q ^ (row & 7);
      *(uint4*)(Bs + (row * 8 + phys) * 16) = o;
    }
    // ---- prefetch x(k+1) into regs (issues before barrier, lands during compute) ----
    if (k < 3) {
      const float4 z = make_float4(0.f, 0.f, 0.f, 0.f);
      const float* gxn = gx + (k + 1) * BK;
      n0 = aval ? *(const float4*)(gxn + 0)  : z;
      n1 = aval ? *(const float4*)(gxn + 4)  : z;
      n2 = aval ? *(const float4*)(gxn + 8)  : z;
      n3 = aval ? *(const float4*)(gxn + 12) : z;
    }
    __syncthreads();

    // ---- compute(k) ----
#pragma unroll
    for (int kk = 0; kk < 2; ++kk) {
      bf16x8 aF[4], bF[4];
      int qq = kk * 4 + (lane >> 4);
#pragma unroll
      for (int rt = 0; rt < 4; ++rt) {
        int r = rt * 16 + (lane & 15);
        int phys = qq ^ (r & 7);
        aF[rt] = *(const bf16x8*)(As + r * 128 + phys * 16);
      }
#pragma unroll
      for (int ct = 0; ct < 4; ++ct) {
        int cl = w * 64 + ct * 16 + (lane & 15);
        int phys = qq ^ (cl & 7);
        bF[ct] = *(const bf16x8*)(Bs + cl * 128 + phys * 16);
      }
#pragma unroll
      for (int rt = 0; rt < 4; ++rt)
#pragma unroll
        for (int ct = 0; ct < 4; ++ct)
          acc[rt][ct] = __builtin_amdgcn_mfma_f32_16x16x32_bf16(aF[rt], bF[ct], acc[rt][ct], 0, 0, 0);
    }
    __syncthreads();
    f0 = n0; f1 = n1; f2 = n2; f3 = n3;
  }

  const int h = w;
  float att_s[4], att_d[4];
#pragma unroll
  for (int ct = 0; ct < 4; ++ct) {
    att_s[ct] = att[h * 2 * CC + ct * 16 + (lane & 15)];
    att_d[ct] = att[h * 2 * CC + CC + ct * 16 + (lane & 15)];
  }
#pragma unroll
  for (int rt = 0; rt < 4; ++rt) {
#pragma unroll
    for (int reg = 0; reg < 4; ++reg) {
      float ls = 0.f, ld_ = 0.f;
#pragma unroll
      for (int ct = 0; ct < 4; ++ct) {
        float a = acc[rt][ct][reg];
        ls += a * att_s[ct];
        ld_ += a * att_d[ct];
      }
#pragma unroll
      for (int off = 1; off < 16; off <<= 1) {
        ls += __shfl_xor(ls, off);
        ld_ += __shfl_xor(ld_, off);
      }
      int r = row0 + rt * 16 + (lane >> 4) * 4 + reg;
      if ((lane & 15) == 0 && r < M) {
        s_src[r * HH + h] = ls;
        s_dst[r * HH + h] = ld_;
      }
    }
  }

#pragma unroll
  for (int rt = 0; rt < 4; ++rt) {
#pragma unroll
    for (int reg = 0; reg < 4; ++reg) {
      int r = row0 + rt * 16 + (lane >> 4) * 4 + reg;
      if (r < M) {
#pragma unroll
        for (int ct = 0; ct < 4; ++ct) {
          int ccol = w * 64 + ct * 16 + (lane & 15);
          Wh[(size_t)r * NOUT + ccol] = f2bf(acc[rt][ct][reg]);
        }
      }
    }
  }
}

// ---------------- aggregation: bucket CSR, inline p=exp(leaky(.)), 4-deep MLP, fused ELU ----------------
__global__ __launch_bounds__(256)
void aggregate(const ushort_t* __restrict__ Wh, const float* __restrict__ s_src,
               const float* __restrict__ s_dst, const int* __restrict__ cnt,
               const int* __restrict__ bucket, float* __restrict__ out, int N) {
  int wid = (int)((blockIdx.x * 256 + threadIdx.x) >> 6);
  int lane = threadIdx.x & 63;
  if (wid >= N) return;
  int half = lane >> 5, cl = lane & 31;
  int h = cl >> 3;
  int deg = cnt[wid];
  if (deg > CAP) deg = CAP;
  int start = wid * CAP;
  int end = start + deg;
  float sd = s_dst[wid * HH + h];
  float acc[8] = {};
  float dsum = 0.f;
  int idx = start + half;
  for (; idx + 6 < end; idx += 8) {
    int s[4];
#pragma unroll
    for (int k = 0; k < 4; ++k) s[k] = bucket[idx + 2 * k];
    float p[4];
    uint4 wv[4];
#pragma unroll
    for (int k = 0; k < 4; ++k) {
      float v = s_src[s[k] * HH + h] + sd;
      v = v > 0.f ? v : 0.2f * v;
      p[k] = __expf(v);
      wv[k] = *(const uint4*)(Wh + (size_t)s[k] * NOUT + cl * 8);
    }
#pragma unroll
    for (int k = 0; k < 4; ++k) {
      dsum += p[k];
#pragma unroll
      for (int j = 0; j < 4; ++j) {
        unsigned u = ((const unsigned*)&wv[k])[j];
        acc[2 * j]     += p[k] * __uint_as_float(u << 16);
        acc[2 * j + 1] += p[k] * __uint_as_float(u & 0xffff0000u);
      }
    }
  }
  for (; idx < end; idx += 2) {
    int s0 = bucket[idx];
    float v = s_src[s0 * HH + h] + sd;
    v = v > 0.f ? v : 0.2f * v;
    float p0 = __expf(v);
    uint4 w0 = *(const uint4*)(Wh + (size_t)s0 * NOUT + cl * 8);
    dsum += p0;
#pragma unroll
    for (int j = 0; j < 4; ++j) {
      unsigned u0 = ((const unsigned*)&w0)[j];
      acc[2 * j]     += p0 * __uint_as_float(u0 << 16);
      acc[2 * j + 1] += p0 * __uint_as_float(u0 & 0xffff0000u);
    }
  }
#pragma unroll
  for (int j = 0; j < 8; ++j) acc[j] += __shfl_xor(acc[j], 32);
  dsum += __shfl_xor(dsum, 32);
  if (half == 0) {
    float rd = 1.0f / (dsum + 1e-16f);
    float o[8];
#pragma unroll
    for (int j = 0; j < 8; ++j) {
      float a = acc[j] * rd;
      o[j] = a > 0.f ? a : expm1f(a);
    }
    float* op = out + (size_t)wid * NOUT + cl * 8;
    *(float4*)op = make_float4(o[0], o[1], o[2], o[3]);
    *(float4*)(op + 4) = make_float4(o[4], o[5], o[6], o[7]);
  }
}

extern "C" void kernel_launch(void* const* d_in, const int* in_sizes, int n_in,
                              void* d_out, int out_size, void* d_ws, size_t ws_size,
                              hipStream_t stream) {
  const float* x = (const float*)d_in[0];
  const int* ei = (const int*)d_in[1];
  const float* W = (const float*)d_in[2];
  const float* att = (const float*)d_in[3];
  float* out = (float*)d_out;
  const int N = in_sizes[0] / KDIM;
  const int E = in_sizes[1] / 2;
  const int NPAD = ((N + BM - 1) / BM) * BM;

  char* p = (char*)d_ws;
  auto alloc = [&](size_t bytes) {
    char* r = p;
    p += (bytes + 255) & ~(size_t)255;
    return r;
  };
  ushort_t* Wh   = (ushort_t*)alloc((size_t)NPAD * NOUT * 2);
  float* s_src   = (float*)alloc((size_t)N * HH * 4);
  float* s_dst   = (float*)alloc((size_t)N * HH * 4);
  int* cnt       = (int*)alloc((size_t)N * 4);
  int* bucket    = (int*)alloc((size_t)N * CAP * 4);

  gemm_direct<<<NPAD / BM, 256, 0, stream>>>(x, W, Wh, s_src, s_dst, att, N, cnt, N);

  scatter_k<<<(E + 255) / 256, 256, 0, stream>>>(ei, cnt, bucket, E);

  aggregate<<<(N + 3) / 4, 256, 0, stream>>>(Wh, s_src, s_dst, cnt, bucket, out, N);
}

// Round 17
// 151.971 us; speedup vs baseline: 1.0065x; 1.0065x over previous
//
#include <hip/hip_runtime.h>
#include <hip/hip_bf16.h>
#include <cstdint>

#define HH 4
#define CC 64
#define KDIM 256   // IN_CH
#define NOUT 256   // H*C
#define BM 32
#define BK 64
#define CAP 64     // max degree capacity (Poisson(16): P(deg>=64) ~ 2e-18)

typedef __attribute__((ext_vector_type(8))) short bf16x8;
typedef __attribute__((ext_vector_type(4))) float f32x4;
typedef unsigned short ushort_t;

__device__ __forceinline__ unsigned short f2bf(float f) {
  unsigned u = __float_as_uint(f);
  unsigned r = (u + 0x7fff + ((u >> 16) & 1)) >> 16;  // RNE
  return (unsigned short)r;
}
__device__ __forceinline__ unsigned pk2bf(float lo, float hi) {
  return (unsigned)f2bf(lo) | ((unsigned)f2bf(hi) << 16);
}

// ---------------- pure bucket-CSR scatter ----------------
__global__ __launch_bounds__(256)
void scatter_k(const int* __restrict__ ei, int* __restrict__ cnt,
               int* __restrict__ bucket, int E) {
  int t = (int)blockIdx.x * 256 + threadIdx.x;
  if (t < E) {
    int s = ei[t];
    int d = ei[E + t];
    int pos = atomicAdd(&cnt[d], 1);
    if (pos < CAP) bucket[(size_t)d * CAP + pos] = s;
  }
}

// ---------------- MFMA GEMM 32x256: Wh(bf16) = x(fp32) @ W(fp32)^T + fused scores ----------------
// One block = 32 rows x all 256 cols; wave w owns head w. x read exactly once.
// Smaller row-tile -> 2x blocks (1563) + 36KB LDS -> 4 blocks/CU: better latency hiding.
__global__ __launch_bounds__(256)
void gemm_direct(const float* __restrict__ X, const float* __restrict__ W,
                 ushort_t* __restrict__ Wh, float* __restrict__ s_src,
                 float* __restrict__ s_dst, const float* __restrict__ att,
                 int M, int* __restrict__ cnt, int N) {
  __shared__ char As[BM * BK * 2];       // 4 KB
  __shared__ char Bs[NOUT * BK * 2];     // 32 KB
  const int tid = threadIdx.x;
  const int lane = tid & 63;
  const int w = tid >> 6;
  const int row0 = blockIdx.x * BM;

  // zero cnt slice (next dispatch depends on it): 1563 blocks x 32 >= N
  if (tid < BM) {
    int i = (int)blockIdx.x * BM + tid;
    if (i < N) cnt[i] = 0;
  }

  const int arow = tid >> 3;             // 0..31
  const int aq = tid & 7;                // k-group
  const bool aval = (row0 + arow) < M;
  const float* gx = X + (size_t)(row0 + arow) * KDIM + aq * 8;

  f32x4 acc[2][4] = {};

  for (int k0 = 0; k0 < KDIM; k0 += BK) {
    // ---- stage A: 32x64 fp32 -> bf16 LDS (XOR-swizzled 16B groups) ----
    {
      float4 g0 = make_float4(0.f, 0.f, 0.f, 0.f), g1 = g0;
      if (aval) {
        g0 = *(const float4*)(gx + k0);
        g1 = *(const float4*)(gx + k0 + 4);
      }
      uint4 o;
      o.x = pk2bf(g0.x, g0.y); o.y = pk2bf(g0.z, g0.w);
      o.z = pk2bf(g1.x, g1.y); o.w = pk2bf(g1.z, g1.w);
      int phys = aq ^ (arow & 7);
      *(uint4*)(As + (arow * 8 + phys) * 16) = o;
    }
    // ---- stage B: 256x64 fp32 W -> bf16 LDS (L2-resident source) ----
#pragma unroll
    for (int i = 0; i < 8; ++i) {
      int c = i * 256 + tid;
      int row = c >> 3, q = c & 7;
      const float* gw = W + (size_t)row * KDIM + k0 + q * 8;
      float4 g0 = *(const float4*)gw;
      float4 g1 = *(const float4*)(gw + 4);
      uint4 o;
      o.x = pk2bf(g0.x, g0.y); o.y = pk2bf(g0.z, g0.w);
      o.z = pk2bf(g1.x, g1.y); o.w = pk2bf(g1.z, g1.w);
      int phys = q ^ (row & 7);
      *(uint4*)(Bs + (row * 8 + phys) * 16) = o;
    }
    __syncthreads();

#pragma unroll
    for (int kk = 0; kk < 2; ++kk) {
      bf16x8 aF[2], bF[4];
      int qq = kk * 4 + (lane >> 4);
#pragma unroll
      for (int rt = 0; rt < 2; ++rt) {
        int r = rt * 16 + (lane & 15);
        int phys = qq ^ (r & 7);
        aF[rt] = *(const bf16x8*)(As + r * 128 + phys * 16);
      }
#pragma unroll
      for (int ct = 0; ct < 4; ++ct) {
        int cl = w * 64 + ct * 16 + (lane & 15);
        int phys = qq ^ (cl & 7);
        bF[ct] = *(const bf16x8*)(Bs + cl * 128 + phys * 16);
      }
#pragma unroll
      for (int rt = 0; rt < 2; ++rt)
#pragma unroll
        for (int ct = 0; ct < 4; ++ct)
          acc[rt][ct] = __builtin_amdgcn_mfma_f32_16x16x32_bf16(aF[rt], bF[ct], acc[rt][ct], 0, 0, 0);
    }
    __syncthreads();
  }

  const int h = w;
  float att_s[4], att_d[4];
#pragma unroll
  for (int ct = 0; ct < 4; ++ct) {
    att_s[ct] = att[h * 2 * CC + ct * 16 + (lane & 15)];
    att_d[ct] = att[h * 2 * CC + CC + ct * 16 + (lane & 15)];
  }
#pragma unroll
  for (int rt = 0; rt < 2; ++rt) {
#pragma unroll
    for (int reg = 0; reg < 4; ++reg) {
      float ls = 0.f, ld_ = 0.f;
#pragma unroll
      for (int ct = 0; ct < 4; ++ct) {
        float a = acc[rt][ct][reg];
        ls += a * att_s[ct];
        ld_ += a * att_d[ct];
      }
#pragma unroll
      for (int off = 1; off < 16; off <<= 1) {
        ls += __shfl_xor(ls, off);
        ld_ += __shfl_xor(ld_, off);
      }
      int r = row0 + rt * 16 + (lane >> 4) * 4 + reg;
      if ((lane & 15) == 0 && r < M) {
        s_src[r * HH + h] = ls;
        s_dst[r * HH + h] = ld_;
      }
    }
  }

#pragma unroll
  for (int rt = 0; rt < 2; ++rt) {
#pragma unroll
    for (int reg = 0; reg < 4; ++reg) {
      int r = row0 + rt * 16 + (lane >> 4) * 4 + reg;
      if (r < M) {
#pragma unroll
        for (int ct = 0; ct < 4; ++ct) {
          int ccol = w * 64 + ct * 16 + (lane & 15);
          Wh[(size_t)r * NOUT + ccol] = f2bf(acc[rt][ct][reg]);
        }
      }
    }
  }
}

// ---------------- aggregation: bucket CSR, inline p=exp(leaky(.)), 4-deep MLP, fused ELU ----------------
__global__ __launch_bounds__(256)
void aggregate(const ushort_t* __restrict__ Wh, const float* __restrict__ s_src,
               const float* __restrict__ s_dst, const int* __restrict__ cnt,
               const int* __restrict__ bucket, float* __restrict__ out, int N) {
  int wid = (int)((blockIdx.x * 256 + threadIdx.x) >> 6);
  int lane = threadIdx.x & 63;
  if (wid >= N) return;
  int half = lane >> 5, cl = lane & 31;
  int h = cl >> 3;
  int deg = cnt[wid];
  if (deg > CAP) deg = CAP;
  int start = wid * CAP;
  int end = start + deg;
  float sd = s_dst[wid * HH + h];
  float acc[8] = {};
  float dsum = 0.f;
  int idx = start + half;
  for (; idx + 6 < end; idx += 8) {
    int s[4];
#pragma unroll
    for (int k = 0; k < 4; ++k) s[k] = bucket[idx + 2 * k];
    float p[4];
    uint4 wv[4];
#pragma unroll
    for (int k = 0; k < 4; ++k) {
      float v = s_src[s[k] * HH + h] + sd;
      v = v > 0.f ? v : 0.2f * v;
      p[k] = __expf(v);
      wv[k] = *(const uint4*)(Wh + (size_t)s[k] * NOUT + cl * 8);
    }
#pragma unroll
    for (int k = 0; k < 4; ++k) {
      dsum += p[k];
#pragma unroll
      for (int j = 0; j < 4; ++j) {
        unsigned u = ((const unsigned*)&wv[k])[j];
        acc[2 * j]     += p[k] * __uint_as_float(u << 16);
        acc[2 * j + 1] += p[k] * __uint_as_float(u & 0xffff0000u);
      }
    }
  }
  for (; idx < end; idx += 2) {
    int s0 = bucket[idx];
    float v = s_src[s0 * HH + h] + sd;
    v = v > 0.f ? v : 0.2f * v;
    float p0 = __expf(v);
    uint4 w0 = *(const uint4*)(Wh + (size_t)s0 * NOUT + cl * 8);
    dsum += p0;
#pragma unroll
    for (int j = 0; j < 4; ++j) {
      unsigned u0 = ((const unsigned*)&w0)[j];
      acc[2 * j]     += p0 * __uint_as_float(u0 << 16);
      acc[2 * j + 1] += p0 * __uint_as_float(u0 & 0xffff0000u);
    }
  }
#pragma unroll
  for (int j = 0; j < 8; ++j) acc[j] += __shfl_xor(acc[j], 32);
  dsum += __shfl_xor(dsum, 32);
  if (half == 0) {
    float rd = 1.0f / (dsum + 1e-16f);
    float o[8];
#pragma unroll
    for (int j = 0; j < 8; ++j) {
      float a = acc[j] * rd;
      o[j] = a > 0.f ? a : expm1f(a);
    }
    float* op = out + (size_t)wid * NOUT + cl * 8;
    *(float4*)op = make_float4(o[0], o[1], o[2], o[3]);
    *(float4*)(op + 4) = make_float4(o[4], o[5], o[6], o[7]);
  }
}

extern "C" void kernel_launch(void* const* d_in, const int* in_sizes, int n_in,
                              void* d_out, int out_size, void* d_ws, size_t ws_size,
                              hipStream_t stream) {
  const float* x = (const float*)d_in[0];
  const int* ei = (const int*)d_in[1];
  const float* W = (const float*)d_in[2];
  const float* att = (const float*)d_in[3];
  float* out = (float*)d_out;
  const int N = in_sizes[0] / KDIM;
  const int E = in_sizes[1] / 2;
  const int NPAD = ((N + BM - 1) / BM) * BM;

  char* p = (char*)d_ws;
  auto alloc = [&](size_t bytes) {
    char* r = p;
    p += (bytes + 255) & ~(size_t)255;
    return r;
  };
  ushort_t* Wh   = (ushort_t*)alloc((size_t)NPAD * NOUT * 2);
  float* s_src   = (float*)alloc((size_t)N * HH * 4);
  float* s_dst   = (float*)alloc((size_t)N * HH * 4);
  int* cnt       = (int*)alloc((size_t)N * 4);
  int* bucket    = (int*)alloc((size_t)N * CAP * 4);

  gemm_direct<<<NPAD / BM, 256, 0, stream>>>(x, W, Wh, s_src, s_dst, att, N, cnt, N);

  scatter_k<<<(E + 255) / 256, 256, 0, stream>>>(ei, cnt, bucket, E);

  aggregate<<<(N + 3) / 4, 256, 0, stream>>>(Wh, s_src, s_dst, cnt, bucket, out, N);
}